// Round 5
// baseline (187.514 us; speedup 1.0000x reference)
//
#include <hip/hip_runtime.h>
#include <hip/hip_fp16.h>

// MultiScaleRoIAlign (round 5).
// Pass 1 (repack v2): [B,C,H,W] fp32 -> ws [B, hw, C] fp16, fully vectorized:
//   float4 global reads, LDS fp32 tile (pitch 65 -> 2-way-free banks), half8
//   (16B) global writes. Edge tiles take a guarded scalar path.
// Pass 2 (main v2): block = (roi, bin-quarter of 13). Lane owns 4 consecutive
//   channels; each bilinear corner is one 8B coalesced load. 13.8 KB LDS ->
//   ~8 blocks/CU. Coalesced writeout via [c][bin] LDS tile.

#define ROI_OUT 7
#define NSAMP   14
#define C_TOT   256
#define N_PER_B 256
#define BINS    49
#define QBINS   13
#define TOT_HW  53125          // 40000 + 10000 + 2500 + 625 per image
#define NTILE_X 832            // 625 + 157 + 40 + 10 hw-tiles of 64

// ---------------- pass 1: transpose to channels-last fp16 ----------------
__global__ __launch_bounds__(256)
void repack_kernel(const float* __restrict__ f0, const float* __restrict__ f1,
                   const float* __restrict__ f2, const float* __restrict__ f3,
                   __half* __restrict__ ws)
{
    __shared__ float tile[64][65];      // pitch 65 (==1 mod 32)

    const int tx = blockIdx.x;
    const float* feat; int HW, base, hw0;
    if (tx < 625)      { feat = f0; HW = 40000; base = 0;     hw0 = tx * 64; }
    else if (tx < 782) { feat = f1; HW = 10000; base = 40000; hw0 = (tx - 625) * 64; }
    else if (tx < 822) { feat = f2; HW = 2500;  base = 50000; hw0 = (tx - 782) * 64; }
    else               { feat = f3; HW = 625;   base = 52500; hw0 = (tx - 822) * 64; }

    const int c0  = blockIdx.y * 64;
    const int b   = blockIdx.z;
    const int tid = threadIdx.x;
    const float* src = feat + (size_t)(b * C_TOT + c0) * (size_t)HW;

    const int cl = tid >> 4;            // 0..15
    const int hl = (tid & 15) * 4;      // 0..60

    if (hw0 + 64 <= HW) {               // block-uniform fast path
        #pragma unroll
        for (int i = 0; i < 4; ++i) {
            int cc = cl + 16 * i;
            float4 v = *(const float4*)(src + (size_t)cc * HW + (hw0 + hl));
            *(float4*)&tile[cc][hl] = v;
        }
    } else {                            // edge tile: guarded scalar
        #pragma unroll
        for (int i = 0; i < 4; ++i) {
            int cc = cl + 16 * i;
            #pragma unroll
            for (int j = 0; j < 4; ++j) {
                int hw = hw0 + hl + j;
                tile[cc][hl + j] = (hw < HW) ? src[(size_t)cc * HW + hw] : 0.0f;
            }
        }
    }
    __syncthreads();

    // write: 8 lanes x half8(16B) cover one hw-row's 64 channels (128B)
    __half* dst = ws + ((size_t)b * TOT_HW + base) * C_TOT + c0;
    const int co  = (tid & 7) * 8;
    const int ho0 = tid >> 3;           // 0..31
    #pragma unroll
    for (int i = 0; i < 2; ++i) {
        int ho  = ho0 + 32 * i;
        int hw2 = hw0 + ho;
        if (hw2 < HW) {
            // bank = (co+k) + ho (mod 32) -> each bank hit exactly 2x/wave: free
            __half2 h0 = __floats2half2_rn(tile[co + 0][ho], tile[co + 1][ho]);
            __half2 h1 = __floats2half2_rn(tile[co + 2][ho], tile[co + 3][ho]);
            __half2 h2 = __floats2half2_rn(tile[co + 4][ho], tile[co + 5][ho]);
            __half2 h3 = __floats2half2_rn(tile[co + 6][ho], tile[co + 7][ho]);
            int4 pk;
            pk.x = *(int*)&h0; pk.y = *(int*)&h1;
            pk.z = *(int*)&h2; pk.w = *(int*)&h3;
            *(int4*)(dst + (size_t)hw2 * C_TOT + co) = pk;
        }
    }
}

// ---------------- pass 2: per-(roi, bin-quarter) pooled gather ----------------
__global__ __launch_bounds__(256)
void msroi_main(const __half* __restrict__ ws, const float* __restrict__ boxes,
                float* __restrict__ out)
{
    __shared__ float oacc[C_TOT * QBINS];   // [c][bin-local], 13312 B
    __shared__ int4  pY[NSAMP], pX[NSAMP];

    const int tid = threadIdx.x;
    const int roi = blockIdx.x >> 2;
    const int q   = blockIdx.x & 3;
    const int b   = roi >> 8;

    const float* bxp = boxes + (size_t)roi * 4;
    float bx1 = bxp[0], by1 = bxp[1], bx2 = bxp[2], by2 = bxp[3];
    float area = (bx2 - bx1) * (by2 - by1);
    float s    = sqrtf(area);
    float lvlf = floorf(4.0f + log2f(s * (1.0f / 224.0f)) + 1e-6f);
    lvlf = fminf(fmaxf(lvlf, 2.0f), 5.0f);
    int level = (int)lvlf - 2;

    int H, W, lvbase; float scale;
    switch (level) {
        case 0:  H = 200; W = 200; lvbase = 0;     scale = 0.25f;    break;
        case 1:  H = 100; W = 100; lvbase = 40000; scale = 0.125f;   break;
        case 2:  H = 50;  W = 50;  lvbase = 50000; scale = 0.0625f;  break;
        default: H = 25;  W = 25;  lvbase = 52500; scale = 0.03125f; break;
    }

    float x1 = bx1 * scale, y1 = by1 * scale;
    float roi_w = fmaxf(bx2 * scale - x1, 1.0f);
    float roi_h = fmaxf(by2 * scale - y1, 1.0f);
    float bin_w = roi_w * (1.0f / ROI_OUT);
    float bin_h = roi_h * (1.0f / ROI_OUT);

    if (tid < 2 * NSAMP) {
        bool isy = tid >= NSAMP;
        int  j   = isy ? tid - NSAMP : tid;
        int  pb  = j >> 1, sub = j & 1;
        float start = isy ? y1 : x1;
        float bsz   = isy ? bin_h : bin_w;
        int   lim   = isy ? H : W;
        float ss = start + (float)pb * bsz + ((float)sub + 0.5f) * bsz * 0.5f;
        float v  = (ss >= -1.0f && ss <= (float)lim) ? 1.0f : 0.0f;
        float cc = fminf(fmaxf(ss, 0.0f), (float)lim - 1.0f);
        int   i0 = (int)floorf(cc);
        int   i1 = min(i0 + 1, lim - 1);
        float l  = cc - (float)i0;
        int4 pk; pk.x = i0; pk.y = i1;
        pk.z = __float_as_int(l); pk.w = __float_as_int(v);
        if (isy) pY[j] = pk; else pX[j] = pk;
    }
    __syncthreads();

    const int b0   = q * QBINS;
    const int bend = min(b0 + QBINS, BINS);
    const int wave = tid >> 6;
    const int lane = tid & 63;
    const int c    = lane * 4;
    const __half* bas = ws + ((size_t)b * TOT_HW + lvbase) * C_TOT + c;

    for (int bin = b0 + wave; bin < bend; bin += 4) {
        int ph = bin / ROI_OUT;
        int pw = bin - ph * ROI_OUT;
        float a0 = 0.f, a1 = 0.f, a2 = 0.f, a3 = 0.f;

        #pragma unroll
        for (int sy = 0; sy < 2; ++sy) {
            int4 py  = pY[2 * ph + sy];
            float ly = __int_as_float(py.z);
            float vy = __int_as_float(py.w);
            float hy = 1.0f - ly;
            #pragma unroll
            for (int sx = 0; sx < 2; ++sx) {
                int4 px  = pX[2 * pw + sx];
                float lx = __int_as_float(px.z);
                float vv = vy * __int_as_float(px.w);
                float hx = 1.0f - lx;
                float w00 = vv * hy * hx, w01 = vv * hy * lx;
                float w10 = vv * ly * hx, w11 = vv * ly * lx;

                int2 r00 = *(const int2*)(bas + (size_t)(py.x * W + px.x) * C_TOT);
                int2 r01 = *(const int2*)(bas + (size_t)(py.x * W + px.y) * C_TOT);
                int2 r10 = *(const int2*)(bas + (size_t)(py.y * W + px.x) * C_TOT);
                int2 r11 = *(const int2*)(bas + (size_t)(py.y * W + px.y) * C_TOT);

                float2 g0, g1;
                g0 = __half22float2(*(__half2*)&r00.x); g1 = __half22float2(*(__half2*)&r00.y);
                a0 += w00 * g0.x; a1 += w00 * g0.y; a2 += w00 * g1.x; a3 += w00 * g1.y;
                g0 = __half22float2(*(__half2*)&r01.x); g1 = __half22float2(*(__half2*)&r01.y);
                a0 += w01 * g0.x; a1 += w01 * g0.y; a2 += w01 * g1.x; a3 += w01 * g1.y;
                g0 = __half22float2(*(__half2*)&r10.x); g1 = __half22float2(*(__half2*)&r10.y);
                a0 += w10 * g0.x; a1 += w10 * g0.y; a2 += w10 * g1.x; a3 += w10 * g1.y;
                g0 = __half22float2(*(__half2*)&r11.x); g1 = __half22float2(*(__half2*)&r11.y);
                a0 += w11 * g0.x; a1 += w11 * g0.y; a2 += w11 * g1.x; a3 += w11 * g1.y;
            }
        }
        int bl = bin - b0;
        oacc[(c + 0) * QBINS + bl] = a0 * 0.25f;
        oacc[(c + 1) * QBINS + bl] = a1 * 0.25f;
        oacc[(c + 2) * QBINS + bl] = a2 * 0.25f;
        oacc[(c + 3) * QBINS + bl] = a3 * 0.25f;
    }
    __syncthreads();

    // writeout: consecutive j -> runs of up to 13 consecutive floats in out
    float* ob = out + (size_t)roi * (C_TOT * BINS);
    const int nb = bend - b0;
    for (int j = tid; j < C_TOT * QBINS; j += 256) {
        int cc = j / QBINS;             // constant divisor -> magic mul
        int bl = j - cc * QBINS;
        if (bl < nb) ob[cc * BINS + b0 + bl] = oacc[j];
    }
}

// ---------------- fallback: direct gather (ws too small) ----------------
__global__ __launch_bounds__(256)
void msroi_direct(const float* __restrict__ f0, const float* __restrict__ f1,
                  const float* __restrict__ f2, const float* __restrict__ f3,
                  const float* __restrict__ boxes, float* __restrict__ out, int total)
{
    int e = blockIdx.x * 256 + threadIdx.x;
    if (e >= total) return;
    int bin = e % BINS;
    int c   = (e / BINS) % C_TOT;
    int roi = e / (BINS * C_TOT);
    int b   = roi / N_PER_B;

    const float* bx = boxes + (size_t)roi * 4;
    float bx1 = bx[0], by1 = bx[1], bx2 = bx[2], by2 = bx[3];
    float area = (bx2 - bx1) * (by2 - by1);
    float s    = sqrtf(area);
    float lvlf = floorf(4.0f + log2f(s * (1.0f / 224.0f)) + 1e-6f);
    lvlf = fminf(fmaxf(lvlf, 2.0f), 5.0f);
    int level = (int)lvlf - 2;

    const float* feat; int H, W; float scale;
    switch (level) {
        case 0:  feat = f0; H = 200; W = 200; scale = 0.25f;    break;
        case 1:  feat = f1; H = 100; W = 100; scale = 0.125f;   break;
        case 2:  feat = f2; H = 50;  W = 50;  scale = 0.0625f;  break;
        default: feat = f3; H = 25;  W = 25;  scale = 0.03125f; break;
    }
    float x1 = bx1 * scale, y1 = by1 * scale;
    float roi_w = fmaxf(bx2 * scale - x1, 1.0f);
    float roi_h = fmaxf(by2 * scale - y1, 1.0f);
    float bin_w = roi_w * (1.0f / ROI_OUT);
    float bin_h = roi_h * (1.0f / ROI_OUT);
    int ph = bin / ROI_OUT, pw = bin - ph * ROI_OUT;
    const float* plane = feat + ((size_t)(b * C_TOT + c)) * (size_t)(H * W);
    float Hf = (float)H, Wf = (float)W, acc = 0.0f;
    #pragma unroll
    for (int sy = 0; sy < 2; ++sy) {
        float ys = y1 + (float)ph * bin_h + ((float)sy + 0.5f) * bin_h * 0.5f;
        float vy = (ys >= -1.0f && ys <= Hf) ? 1.0f : 0.0f;
        float y  = fminf(fmaxf(ys, 0.0f), Hf - 1.0f);
        int   y0 = (int)floorf(y);
        int   y1i = min(y0 + 1, H - 1);
        float ly = y - (float)y0, hy = 1.0f - ly;
        int ro0 = y0 * W, ro1 = y1i * W;
        #pragma unroll
        for (int sx = 0; sx < 2; ++sx) {
            float xs = x1 + (float)pw * bin_w + ((float)sx + 0.5f) * bin_w * 0.5f;
            float vx = (xs >= -1.0f && xs <= Wf) ? 1.0f : 0.0f;
            float x  = fminf(fmaxf(xs, 0.0f), Wf - 1.0f);
            int   x0 = (int)floorf(x);
            int   x1i = min(x0 + 1, W - 1);
            float lx = x - (float)x0, hx = 1.0f - lx;
            float v00 = plane[ro0 + x0],  v01 = plane[ro0 + x1i];
            float v10 = plane[ro1 + x0],  v11 = plane[ro1 + x1i];
            acc += vy * vx * (hy * (hx * v00 + lx * v01) + ly * (hx * v10 + lx * v11));
        }
    }
    out[e] = acc * 0.25f;
}

extern "C" void kernel_launch(void* const* d_in, const int* in_sizes, int n_in,
                              void* d_out, int out_size, void* d_ws, size_t ws_size,
                              hipStream_t stream)
{
    const float* f0    = (const float*)d_in[0];
    const float* f1    = (const float*)d_in[1];
    const float* f2    = (const float*)d_in[2];
    const float* f3    = (const float*)d_in[3];
    const float* boxes = (const float*)d_in[4];
    float* out = (float*)d_out;

    const size_t ws_needed = (size_t)2 * TOT_HW * C_TOT * sizeof(__half); // 54.4 MB
    if (ws_size >= ws_needed) {
        __half* ws = (__half*)d_ws;
        hipLaunchKernelGGL(repack_kernel, dim3(NTILE_X, 4, 2), dim3(256), 0, stream,
                           f0, f1, f2, f3, ws);
        hipLaunchKernelGGL(msroi_main, dim3(2 * N_PER_B * 4), dim3(256), 0, stream,
                           ws, boxes, out);
    } else {
        int total = out_size;
        hipLaunchKernelGGL(msroi_direct, dim3((total + 255) / 256), dim3(256), 0, stream,
                           f0, f1, f2, f3, boxes, out, total);
    }
}